// Round 8
// baseline (78.069 us; speedup 1.0000x reference)
//
#include <hip/hip_runtime.h>
#include <math.h>

#define HW 224
#define NCOL 56   // distinct DCT columns needed: {32*b + c : b in 0..6, c in 0..7}

// Orthonormal DCT-II matrix element M[r][k], exact integer range reduction.
__device__ __forceinline__ float dctM(int r, int k) {
    int m = ((2 * k + 1) * r) % (4 * HW);               // m in [0, 896)
    float ang = (float)m * (3.14159265358979323846f / (2.0f * HW));
    float v = cosf(ang);
    v *= (r == 0) ? 0.06681531047810609f : 0.09449111825230679f;
    return v;
}

__device__ __forceinline__ float gray_px(float r, float g, float b) {
    float ru = floorf(r * 255.f);
    float gu = floorf(g * 255.f);
    float bu = floorf(b * 255.f);
    return rintf(fmaf(0.299f, ru, fmaf(0.587f, gu, 0.114f * bu)));
}

// K0 DIAGNOSTIC PROBE: stream the full image footprint (pure reads).
// zw is a runtime zero (fminf(0,|w1[0]|)) so the compiler cannot fold the
// loads away. Its dur_us delta vs next round = steady-state image read time.
__global__ __launch_bounds__(256) void k0_probe(const float* __restrict__ img,
                                                const float* __restrict__ w1,
                                                float* __restrict__ sink) {
    const float zw = fminf(0.0f, fabsf(w1[0]));
    const int nf4 = (8 * 32 * 3 * HW * HW) / 4;   // 9.63M float4s
    float s = 0.f;
    for (int i = blockIdx.x * 256 + threadIdx.x; i < nf4; i += 2048 * 256) {
        float4 v = ((const float4*)img)[i];
        s += v.x + v.y + v.z + v.w;
    }
    if (threadIdx.x == 0) sink[blockIdx.x] = s * zw;
}

// K1: block = (frame, strip of 28 rows). grid = 2048, 256 threads, 14.8 KB LDS.
__global__ __launch_bounds__(256) void k1_rowproj(const float* __restrict__ img,
                                                  float* __restrict__ gpart) {
    __shared__ float msel[4 * 28];
    __shared__ float part[4][4 * HW];

    const int tid = threadIdx.x;
    const int bid = blockIdx.x;
    const int frame = bid >> 3, strip = bid & 7;

    if (tid < 112) {
        int i = tid / 28, hh = tid % 28;
        int r = (i < 2) ? i : (30 + i);   // 0,1,32,33
        msel[i * 28 + hh] = dctM(r, strip * 28 + hh);
    }
    __syncthreads();

    const int cg = tid & 63;    // col group (float4), active < 56
    const int sub = tid >> 6;   // 0..3, 7 rows each
    if (cg < 56) {
        const float* p = img + (size_t)frame * (3 * HW * HW)
                       + (strip * 28 + sub * 7) * HW + cg * 4;
        float4 a0 = {0, 0, 0, 0}, a1 = {0, 0, 0, 0}, a2 = {0, 0, 0, 0}, a3 = {0, 0, 0, 0};
        #pragma unroll
        for (int h = 0; h < 7; ++h) {
            const float4 r4 = *(const float4*)(p + h * HW);
            const float4 g4 = *(const float4*)(p + HW * HW + h * HW);
            const float4 b4 = *(const float4*)(p + 2 * HW * HW + h * HW);
            float gx = gray_px(r4.x, g4.x, b4.x);
            float gy = gray_px(r4.y, g4.y, b4.y);
            float gz = gray_px(r4.z, g4.z, b4.z);
            float gw = gray_px(r4.w, g4.w, b4.w);
            int hh = sub * 7 + h;
            float m0 = msel[0 * 28 + hh];
            float m1 = msel[1 * 28 + hh];
            float m2 = msel[2 * 28 + hh];
            float m3 = msel[3 * 28 + hh];
            a0.x += m0 * gx; a0.y += m0 * gy; a0.z += m0 * gz; a0.w += m0 * gw;
            a1.x += m1 * gx; a1.y += m1 * gy; a1.z += m1 * gz; a1.w += m1 * gw;
            a2.x += m2 * gx; a2.y += m2 * gy; a2.z += m2 * gz; a2.w += m2 * gw;
            a3.x += m3 * gx; a3.y += m3 * gy; a3.z += m3 * gz; a3.w += m3 * gw;
        }
        float* tp = part[sub] + cg * 4;
        *(float4*)(tp + 0 * HW) = a0;
        *(float4*)(tp + 1 * HW) = a1;
        *(float4*)(tp + 2 * HW) = a2;
        *(float4*)(tp + 3 * HW) = a3;
    }
    __syncthreads();

    for (int idx = tid; idx < 4 * HW; idx += 256)
        gpart[(size_t)bid * 896 + idx] =
            part[0][idx] + part[1][idx] + part[2][idx] + part[3][idx];
}

// K2: per frame (256 blocks x 256 thr): mcol (in-LDS cosf, no extra launch)
// -> strip reduce -> col projection -> feats -> fc1 -> hbuf. No fc2 here
// (per-frame fc2 = 201 MB L2 re-reads, the R7 regression).
__global__ __launch_bounds__(256) void k2_feats_fc1(const float* __restrict__ gpart,
                                                    const float* __restrict__ w1,
                                                    const float* __restrict__ b1,
                                                    float* __restrict__ hbuf) {
    __shared__ float tmp[4 * HW];       // 3.5 KB
    __shared__ float mcol[HW * NCOL];   // 49 KB [w][jj]
    __shared__ float feats[128];

    const int tid = threadIdx.x;
    const int frame = blockIdx.x;

    // mcol table (12544 entries, ~49 cosf/thread)
    for (int idx = tid; idx < HW * NCOL; idx += 256) {
        int w = idx / NCOL, jj = idx % NCOL;
        int j = ((jj >> 3) << 5) + (jj & 7);   // 32*b + c
        mcol[idx] = dctM(j, w);
    }
    // reduce 8 strip partials -> tmp[4][224]
    if (tid < 224) {
        const float4* g = (const float4*)(gpart + (size_t)frame * 8 * 896) + tid;
        float4 s = g[0];
        #pragma unroll
        for (int st = 1; st < 8; ++st) {
            float4 v = g[st * 224];
            s.x += v.x; s.y += v.y; s.z += v.z; s.w += v.w;
        }
        ((float4*)tmp)[tid] = s;
    }
    __syncthreads();

    // column projection (4 x 56) -> feats (tmp reads broadcast, mcol coalesced)
    if (tid < 4 * NCOL) {
        int i = tid / NCOL, jj = tid % NCOL;
        float s = 0.f;
        #pragma unroll 16
        for (int w = 0; w < HW; ++w)
            s += tmp[i * HW + w] * mcol[w * NCOL + jj];
        int f = -1;
        if (i < 2)        f = (jj >> 3) * 16 + i * 8 + (jj & 7);
        else if (jj < 8)  f = 112 + (i - 2) * 8 + jj;
        if (f >= 0) feats[f] = s;
    }
    __syncthreads();

    // fc1: thread o -> h[o]; 4 independent accumulators; w1 (128 KB) L2-resident.
    {
        float a0 = 0.f, a1 = 0.f, a2 = 0.f, a3 = 0.f;
        const float4* wrow = (const float4*)(w1 + tid * 128);
        #pragma unroll
        for (int f4 = 0; f4 < 32; f4 += 4) {
            float4 wa = wrow[f4],     xa = *(const float4*)(feats + 4 * f4);
            float4 wb = wrow[f4 + 1], xb = *(const float4*)(feats + 4 * f4 + 4);
            float4 wc = wrow[f4 + 2], xc = *(const float4*)(feats + 4 * f4 + 8);
            float4 wd = wrow[f4 + 3], xd = *(const float4*)(feats + 4 * f4 + 12);
            a0 += wa.x * xa.x + wa.y * xa.y + wa.z * xa.z + wa.w * xa.w;
            a1 += wb.x * xb.x + wb.y * xb.y + wb.z * xb.z + wb.w * xb.w;
            a2 += wc.x * xc.x + wc.y * xc.y + wc.z * xc.z + wc.w * xc.w;
            a3 += wd.x * xd.x + wd.y * xd.y + wd.z * xd.z + wd.w * xd.w;
        }
        hbuf[frame * 256 + tid] = fmaxf(((a0 + a1) + (a2 + a3)) + b1[tid], 0.f);
    }
}

// K3: fc2 GEMM (R6-proven). Block = 32 frames x 32 outputs (grid 8 x 24).
// w2 read once per block from L2 (6.3 MB total), reused x4 in registers.
__global__ __launch_bounds__(256) void k3_fc2(const float* __restrict__ hbuf,
                                              const float* __restrict__ w2,
                                              const float* __restrict__ b2,
                                              float* __restrict__ out) {
    __shared__ float sH[32][260];   // +4 pad

    const int tid = threadIdx.x;
    const int fg = blockIdx.x;   // 0..7
    const int og = blockIdx.y;   // 0..23

    for (int idx = tid; idx < 32 * 64; idx += 256) {
        int r = idx >> 6, c4 = idx & 63;
        float4 v = ((const float4*)(hbuf + (size_t)(fg * 32 + r) * 256))[c4];
        *(float4*)(&sH[r][c4 * 4]) = v;
    }
    __syncthreads();

    const int o = tid & 31;
    const int fq = tid >> 5;     // 0..7 -> frames fq*4..fq*4+3
    const float4* wrow = (const float4*)(w2 + (size_t)(og * 32 + o) * 256);

    float acc0 = 0.f, acc1 = 0.f, acc2 = 0.f, acc3 = 0.f;
    #pragma unroll 4
    for (int k4 = 0; k4 < 64; ++k4) {
        float4 w4 = wrow[k4];
        float4 h0 = *(const float4*)(&sH[fq * 4 + 0][k4 * 4]);
        float4 h1 = *(const float4*)(&sH[fq * 4 + 1][k4 * 4]);
        float4 h2 = *(const float4*)(&sH[fq * 4 + 2][k4 * 4]);
        float4 h3 = *(const float4*)(&sH[fq * 4 + 3][k4 * 4]);
        acc0 += w4.x * h0.x + w4.y * h0.y + w4.z * h0.z + w4.w * h0.w;
        acc1 += w4.x * h1.x + w4.y * h1.y + w4.z * h1.z + w4.w * h1.w;
        acc2 += w4.x * h2.x + w4.y * h2.y + w4.z * h2.z + w4.w * h2.w;
        acc3 += w4.x * h3.x + w4.y * h3.y + w4.z * h3.z + w4.w * h3.w;
    }

    float bb = b2[og * 32 + o];
    out[(size_t)(fg * 32 + fq * 4 + 0) * 768 + og * 32 + o] = acc0 + bb;
    out[(size_t)(fg * 32 + fq * 4 + 1) * 768 + og * 32 + o] = acc1 + bb;
    out[(size_t)(fg * 32 + fq * 4 + 2) * 768 + og * 32 + o] = acc2 + bb;
    out[(size_t)(fg * 32 + fq * 4 + 3) * 768 + og * 32 + o] = acc3 + bb;
}

extern "C" void kernel_launch(void* const* d_in, const int* in_sizes, int n_in,
                              void* d_out, int out_size, void* d_ws, size_t ws_size,
                              hipStream_t stream) {
    const float* img = (const float*)d_in[0];   // [8,32,3,224,224]
    const float* w1  = (const float*)d_in[1];   // [256,128]
    const float* b1  = (const float*)d_in[2];   // [256]
    const float* w2  = (const float*)d_in[3];   // [768,256]
    const float* b2  = (const float*)d_in[4];   // [768]
    float* out = (float*)d_out;                 // [256,768]

    float* gpart = (float*)d_ws;                 // [2048][896] = 7.34 MB
    float* hbuf  = gpart + 2048 * 896;           // [256][256]
    float* sink  = hbuf + 256 * 256;             // [2048] probe sink

    k0_probe<<<2048, 256, 0, stream>>>(img, w1, sink);          // DIAGNOSTIC
    k1_rowproj<<<2048, 256, 0, stream>>>(img, gpart);
    k2_feats_fc1<<<256, 256, 0, stream>>>(gpart, w1, b1, hbuf);
    k3_fc2<<<dim3(8, 24), 256, 0, stream>>>(hbuf, w2, b2, out);
}

// Round 9
// 55.275 us; speedup vs baseline: 1.4124x; 1.4124x over previous
//
#include <hip/hip_runtime.h>
#include <math.h>

#define HW 224
#define NCOL 56   // distinct DCT columns needed: {32*b + c : b in 0..6, c in 0..7}

// Orthonormal DCT-II matrix element M[r][k], exact integer range reduction.
__device__ __forceinline__ float dctM(int r, int k) {
    int m = ((2 * k + 1) * r) % (4 * HW);               // m in [0, 896)
    float ang = (float)m * (3.14159265358979323846f / (2.0f * HW));
    float v = cosf(ang);
    v *= (r == 0) ? 0.06681531047810609f : 0.09449111825230679f;
    return v;
}

__device__ __forceinline__ float gray_px(float r, float g, float b) {
    float ru = floorf(r * 255.f);
    float gu = floorf(g * 255.f);
    float bu = floorf(b * 255.f);
    return rintf(fmaf(0.299f, ru, fmaf(0.587f, gu, 0.114f * bu)));
}

// K1: block = (frame, strip of 28 rows). grid = 2048, 256 threads.
// __launch_bounds__(256, 8): min 8 waves/EU = 32 waves/CU -> VGPR cap 64.
// Live set ~40 regs (4 acc float4 + 1 rgb triple + addrs), so no spill;
// this forbids the compiler's load-hoisting that previously bloated VGPR
// and silently capped occupancy at 8 waves/CU (the ~46 us plateau).
__global__ __launch_bounds__(256, 8) void k1_rowproj(const float* __restrict__ img,
                                                     float* __restrict__ gpart) {
    __shared__ float msel[4 * 28];
    __shared__ float part[4][4 * HW];

    const int tid = threadIdx.x;
    const int bid = blockIdx.x;
    const int frame = bid >> 3, strip = bid & 7;

    if (tid < 112) {
        int i = tid / 28, hh = tid % 28;
        int r = (i < 2) ? i : (30 + i);   // 0,1,32,33
        msel[i * 28 + hh] = dctM(r, strip * 28 + hh);
    }
    __syncthreads();

    const int cg = tid & 63;    // col group (float4), active < 56
    const int sub = tid >> 6;   // 0..3, 7 rows each
    if (cg < 56) {
        const float* p = img + (size_t)frame * (3 * HW * HW)
                       + (strip * 28 + sub * 7) * HW + cg * 4;
        float4 a0 = {0, 0, 0, 0}, a1 = {0, 0, 0, 0}, a2 = {0, 0, 0, 0}, a3 = {0, 0, 0, 0};
        for (int h = 0; h < 7; ++h) {
            const float4 r4 = *(const float4*)(p + h * HW);
            const float4 g4 = *(const float4*)(p + HW * HW + h * HW);
            const float4 b4 = *(const float4*)(p + 2 * HW * HW + h * HW);
            float gx = gray_px(r4.x, g4.x, b4.x);
            float gy = gray_px(r4.y, g4.y, b4.y);
            float gz = gray_px(r4.z, g4.z, b4.z);
            float gw = gray_px(r4.w, g4.w, b4.w);
            int hh = sub * 7 + h;
            float m0 = msel[0 * 28 + hh];
            float m1 = msel[1 * 28 + hh];
            float m2 = msel[2 * 28 + hh];
            float m3 = msel[3 * 28 + hh];
            a0.x += m0 * gx; a0.y += m0 * gy; a0.z += m0 * gz; a0.w += m0 * gw;
            a1.x += m1 * gx; a1.y += m1 * gy; a1.z += m1 * gz; a1.w += m1 * gw;
            a2.x += m2 * gx; a2.y += m2 * gy; a2.z += m2 * gz; a2.w += m2 * gw;
            a3.x += m3 * gx; a3.y += m3 * gy; a3.z += m3 * gz; a3.w += m3 * gw;
        }
        float* tp = part[sub] + cg * 4;
        *(float4*)(tp + 0 * HW) = a0;
        *(float4*)(tp + 1 * HW) = a1;
        *(float4*)(tp + 2 * HW) = a2;
        *(float4*)(tp + 3 * HW) = a3;
    }
    __syncthreads();

    for (int idx = tid; idx < 4 * HW; idx += 256)
        gpart[(size_t)bid * 896 + idx] =
            part[0][idx] + part[1][idx] + part[2][idx] + part[3][idx];
}

// K2: per frame (256 blocks x 256 thr): mcol (in-LDS cosf) -> strip reduce ->
// col projection -> feats -> fc1 -> hbuf.
__global__ __launch_bounds__(256) void k2_feats_fc1(const float* __restrict__ gpart,
                                                    const float* __restrict__ w1,
                                                    const float* __restrict__ b1,
                                                    float* __restrict__ hbuf) {
    __shared__ float tmp[4 * HW];       // 3.5 KB
    __shared__ float mcol[HW * NCOL];   // 49 KB [w][jj]
    __shared__ float feats[128];

    const int tid = threadIdx.x;
    const int frame = blockIdx.x;

    for (int idx = tid; idx < HW * NCOL; idx += 256) {
        int w = idx / NCOL, jj = idx % NCOL;
        int j = ((jj >> 3) << 5) + (jj & 7);   // 32*b + c
        mcol[idx] = dctM(j, w);
    }
    if (tid < 224) {
        const float4* g = (const float4*)(gpart + (size_t)frame * 8 * 896) + tid;
        float4 s = g[0];
        #pragma unroll
        for (int st = 1; st < 8; ++st) {
            float4 v = g[st * 224];
            s.x += v.x; s.y += v.y; s.z += v.z; s.w += v.w;
        }
        ((float4*)tmp)[tid] = s;
    }
    __syncthreads();

    if (tid < 4 * NCOL) {
        int i = tid / NCOL, jj = tid % NCOL;
        float s = 0.f;
        #pragma unroll 16
        for (int w = 0; w < HW; ++w)
            s += tmp[i * HW + w] * mcol[w * NCOL + jj];
        int f = -1;
        if (i < 2)        f = (jj >> 3) * 16 + i * 8 + (jj & 7);
        else if (jj < 8)  f = 112 + (i - 2) * 8 + jj;
        if (f >= 0) feats[f] = s;
    }
    __syncthreads();

    {
        float a0 = 0.f, a1 = 0.f, a2 = 0.f, a3 = 0.f;
        const float4* wrow = (const float4*)(w1 + tid * 128);
        #pragma unroll
        for (int f4 = 0; f4 < 32; f4 += 4) {
            float4 wa = wrow[f4],     xa = *(const float4*)(feats + 4 * f4);
            float4 wb = wrow[f4 + 1], xb = *(const float4*)(feats + 4 * f4 + 4);
            float4 wc = wrow[f4 + 2], xc = *(const float4*)(feats + 4 * f4 + 8);
            float4 wd = wrow[f4 + 3], xd = *(const float4*)(feats + 4 * f4 + 12);
            a0 += wa.x * xa.x + wa.y * xa.y + wa.z * xa.z + wa.w * xa.w;
            a1 += wb.x * xb.x + wb.y * xb.y + wb.z * xb.z + wb.w * xb.w;
            a2 += wc.x * xc.x + wc.y * xc.y + wc.z * xc.z + wc.w * xc.w;
            a3 += wd.x * xd.x + wd.y * xd.y + wd.z * xd.z + wd.w * xd.w;
        }
        hbuf[frame * 256 + tid] = fmaxf(((a0 + a1) + (a2 + a3)) + b1[tid], 0.f);
    }
}

// K3: fc2 GEMM. Block = 32 frames x 32 outputs (grid 8 x 24), 256 threads.
__global__ __launch_bounds__(256) void k3_fc2(const float* __restrict__ hbuf,
                                              const float* __restrict__ w2,
                                              const float* __restrict__ b2,
                                              float* __restrict__ out) {
    __shared__ float sH[32][260];   // +4 pad

    const int tid = threadIdx.x;
    const int fg = blockIdx.x;   // 0..7
    const int og = blockIdx.y;   // 0..23

    for (int idx = tid; idx < 32 * 64; idx += 256) {
        int r = idx >> 6, c4 = idx & 63;
        float4 v = ((const float4*)(hbuf + (size_t)(fg * 32 + r) * 256))[c4];
        *(float4*)(&sH[r][c4 * 4]) = v;
    }
    __syncthreads();

    const int o = tid & 31;
    const int fq = tid >> 5;     // 0..7 -> frames fq*4..fq*4+3
    const float4* wrow = (const float4*)(w2 + (size_t)(og * 32 + o) * 256);

    float acc0 = 0.f, acc1 = 0.f, acc2 = 0.f, acc3 = 0.f;
    #pragma unroll 4
    for (int k4 = 0; k4 < 64; ++k4) {
        float4 w4 = wrow[k4];
        float4 h0 = *(const float4*)(&sH[fq * 4 + 0][k4 * 4]);
        float4 h1 = *(const float4*)(&sH[fq * 4 + 1][k4 * 4]);
        float4 h2 = *(const float4*)(&sH[fq * 4 + 2][k4 * 4]);
        float4 h3 = *(const float4*)(&sH[fq * 4 + 3][k4 * 4]);
        acc0 += w4.x * h0.x + w4.y * h0.y + w4.z * h0.z + w4.w * h0.w;
        acc1 += w4.x * h1.x + w4.y * h1.y + w4.z * h1.z + w4.w * h1.w;
        acc2 += w4.x * h2.x + w4.y * h2.y + w4.z * h2.z + w4.w * h2.w;
        acc3 += w4.x * h3.x + w4.y * h3.y + w4.z * h3.z + w4.w * h3.w;
    }

    float bb = b2[og * 32 + o];
    out[(size_t)(fg * 32 + fq * 4 + 0) * 768 + og * 32 + o] = acc0 + bb;
    out[(size_t)(fg * 32 + fq * 4 + 1) * 768 + og * 32 + o] = acc1 + bb;
    out[(size_t)(fg * 32 + fq * 4 + 2) * 768 + og * 32 + o] = acc2 + bb;
    out[(size_t)(fg * 32 + fq * 4 + 3) * 768 + og * 32 + o] = acc3 + bb;
}

extern "C" void kernel_launch(void* const* d_in, const int* in_sizes, int n_in,
                              void* d_out, int out_size, void* d_ws, size_t ws_size,
                              hipStream_t stream) {
    const float* img = (const float*)d_in[0];   // [8,32,3,224,224]
    const float* w1  = (const float*)d_in[1];   // [256,128]
    const float* b1  = (const float*)d_in[2];   // [256]
    const float* w2  = (const float*)d_in[3];   // [768,256]
    const float* b2  = (const float*)d_in[4];   // [768]
    float* out = (float*)d_out;                 // [256,768]

    float* gpart = (float*)d_ws;                 // [2048][896] = 7.34 MB
    float* hbuf  = gpart + 2048 * 896;           // [256][256]

    k1_rowproj<<<2048, 256, 0, stream>>>(img, gpart);
    k2_feats_fc1<<<256, 256, 0, stream>>>(gpart, w1, b1, hbuf);
    k3_fc2<<<dim3(8, 24), 256, 0, stream>>>(hbuf, w2, b2, out);
}